// Round 4
// baseline (3812.547 us; speedup 1.0000x reference)
//
#include <hip/hip_runtime.h>

// GRU: T=1024 B=64 D=256 H=512 O=256.
// Round 6: R2 (6-wave, proven 2930us) + targeted latency cuts.
//  (1) only-invalid re-polling: first pass loads the 16KB group tile once;
//      re-poll iterations reload ONLY chunks still showing sentinel. Kills the
//      poll self-congestion (16 WGs x 16KB spin on one L2) that R1/R2 showed
//      to be RT-independent.
//  (2) xa loads issued at step top: the poll fence never waits on HBM.
//  (3) gate math split across all 6 waves by row-index i (gk0:{0,3}, gk1:{1},
//      gk2:{2}); hold[] partitioned accordingly.
//  (4) h stored directly from gate-wave registers as scattered 2B sc0 stores:
//      deletes the h_out LDS bounce, the store-wave specialization and one of
//      three barriers. Sentinel check upgraded to per-16-bit (haszero16) since
//      2B stores make dword visibility non-atomic.
// Exchange protocol (sentinel hs + XCD-consensus fast/slow) unchanged.

#define T_ 1024
#define B_ 64
#define D_ 256
#define H_ 512
#define G_ 1536
#define O_ 256

#define SENT32 0x7FC07FC0u   // bf16 NaN pair: unreachable from f2b(finite)

typedef __attribute__((ext_vector_type(8))) short short8;
typedef __attribute__((ext_vector_type(4))) short short4v;
typedef __attribute__((ext_vector_type(4))) float float4v;
typedef __attribute__((ext_vector_type(4))) unsigned int uint4v;

static __device__ __forceinline__ unsigned short f2b(float f) {
  unsigned u = __builtin_bit_cast(unsigned, f);
  u += 0x7fffu + ((u >> 16) & 1u);          // RNE (finite inputs)
  return (unsigned short)(u >> 16);
}

// ---------------------------------------------------------------- prep ------
__global__ __launch_bounds__(256) void prep_kernel(
    const float* __restrict__ x, const float* __restrict__ Wi,
    const float* __restrict__ Wh, const float* __restrict__ Wo,
    unsigned short* __restrict__ xb, unsigned short* __restrict__ WhT,
    unsigned short* __restrict__ WiT, unsigned short* __restrict__ WoT,
    unsigned short* __restrict__ hs, unsigned* __restrict__ xccbuf)
{
  const size_t NX4 = (size_t)T_ * B_ * D_ / 4;   // float4 -> 4 bf16
  const size_t NWH = (size_t)G_ * H_;
  const size_t NWI = (size_t)G_ * D_;
  const size_t NWO = (size_t)O_ * H_;
  const size_t NH8 = (size_t)T_ * B_ * H_ / 8;   // uint4 sentinel chunks
  const size_t NXC = 256;
  const size_t NTOT = NX4 + NWH + NWI + NWO + NH8 + NXC;
  size_t i = (size_t)blockIdx.x * blockDim.x + threadIdx.x;
  const size_t stride = (size_t)gridDim.x * blockDim.x;
  for (; i < NTOT; i += stride) {
    if (i < NX4) {
      float4v f = ((const float4v*)x)[i];
      short4v o;
      o[0] = (short)f2b(f[0]); o[1] = (short)f2b(f[1]);
      o[2] = (short)f2b(f[2]); o[3] = (short)f2b(f[3]);
      ((short4v*)xb)[i] = o;
      continue;
    }
    size_t j = i - NX4;
    if (j < NWH) { size_t g = j >> 9, k = j & 511; WhT[j] = f2b(Wh[k * G_ + g]); continue; }
    j -= NWH;
    if (j < NWI) { size_t g = j >> 8, k = j & 255; WiT[j] = f2b(Wi[k * G_ + g]); continue; }
    j -= NWI;
    if (j < NWO) { size_t o = j >> 9, k = j & 511; WoT[j] = f2b(Wo[k * O_ + o]); continue; }
    j -= NWO;
    if (j < NH8) {
      uint4v sv = {0x7FC07FC0u, 0x7FC07FC0u, 0x7FC07FC0u, 0x7FC07FC0u};
      ((uint4v*)hs)[j] = sv;
      continue;
    }
    j -= NH8;
    xccbuf[j] = 0u;
  }
}

// ---------------------------------------------------------------- scan ------
// 128 WGs x 384 thr launched; active iff (wg&7)<4 -> 64 active WGs.
// group = wg&7 (16 rows), slice = wg>>3 (32 h-cols). Under round-robin XCD
// dispatch all 16 WGs of a group share one XCD (one shared L2).
// wave = s*3 + gk; wave's gate-cols = gk*512 + slice*32 + s*16.

// per-16-bit sentinel detector: nonzero iff any bf16 half equals 0x7FC0
#define CHKB(V, BAD) do {                                                     \
    uint4v u_ = __builtin_bit_cast(uint4v, V);                                \
    unsigned b_ = 0u;                                                         \
    _Pragma("unroll")                                                         \
    for (int q_ = 0; q_ < 4; ++q_) {                                          \
      unsigned x_ = u_[q_] ^ SENT32;                                          \
      b_ |= (x_ - 0x00010001u) & ~x_ & 0x80008000u;                           \
    }                                                                         \
    BAD = b_;                                                                 \
  } while (0)

#define FENCE3()                                                              \
  asm volatile("s_waitcnt vmcnt(0)"                                           \
               : "+v"(v0), "+v"(v1), "+v"(v2) :: "memory");                   \
  __builtin_amdgcn_sched_barrier(0);

#define POLL(FLAGS)                                                           \
  asm volatile("global_load_dwordx4 %0, %2, off " FLAGS "\n\t"                \
               "global_load_dwordx4 %1, %3, off " FLAGS                       \
               : "=v"(v0), "=v"(v1) : "v"(p0), "v"(p1));                      \
  if (wave < 4)                                                               \
    asm volatile("global_load_dwordx4 %0, %1, off " FLAGS                     \
                 : "=v"(v2) : "v"(p2));                                       \
  FENCE3();                                                                   \
  CHKB(v0, bad0); CHKB(v1, bad1);                                             \
  if (wave < 4) { CHKB(v2, bad2); } else bad2 = 0u;                           \
  while (__any((int)(bad0 | bad1 | bad2) != 0)) {                             \
    if (bad0) asm volatile("global_load_dwordx4 %0, %1, off " FLAGS           \
                           : "=v"(v0) : "v"(p0));                             \
    if (bad1) asm volatile("global_load_dwordx4 %0, %1, off " FLAGS           \
                           : "=v"(v1) : "v"(p1));                             \
    if (bad2) asm volatile("global_load_dwordx4 %0, %1, off " FLAGS           \
                           : "=v"(v2) : "v"(p2));                             \
    FENCE3();                                                                 \
    if (bad0) CHKB(v0, bad0);                                                 \
    if (bad1) CHKB(v1, bad1);                                                 \
    if (bad2) CHKB(v2, bad2);                                                 \
  }

__global__ __launch_bounds__(384, 2) void scan_kernel(
    const unsigned short* __restrict__ xb,
    const unsigned short* __restrict__ WhT,
    const unsigned short* __restrict__ WiT,
    unsigned short* __restrict__ hs,
    const float* __restrict__ bi,
    const float* __restrict__ bhn,
    const float* __restrict__ h0,
    unsigned* __restrict__ xccbuf)
{
  const int wg = blockIdx.x;
  const int group = wg & 7;
  if (group >= 4) return;                     // 64 active WGs on XCDs 0..3
  const int slice = wg >> 3;                  // 0..15
  const int tid = threadIdx.x;
  const int wave = tid >> 6;
  const int lane = tid & 63;
  const int m = lane & 15;
  const int quad = lane >> 4;
  const int gk = wave % 3;
  const int s = wave / 3;
  const int row0 = group * 16;
  const int jbase = slice * 32 + s * 16;
  const int gcol = gk * 512 + jbase + m;

  __shared__ unsigned short hT[16 * 512];     // h tile, XOR-swizzled 16B blocks
  struct HX { float h, x; };
  __shared__ HX lds_hx[6][256];               // pre-activation exchange
  __shared__ int fast_lds;

  // persistent B fragments (weights live in registers for the whole scan)
  short8 Bh[16], Bx[8];
  {
    const unsigned short* p = WhT + (size_t)gcol * H_ + quad * 8;
#pragma unroll
    for (int k = 0; k < 16; ++k) Bh[k] = *(const short8*)(p + k * 32);
    const unsigned short* q = WiT + (size_t)gcol * D_ + quad * 8;
#pragma unroll
    for (int k = 0; k < 8; ++k) Bx[k] = *(const short8*)(q + k * 32);
  }

  const int jcol = jbase + m;
  const float bi_r = bi[jcol];
  const float bi_z = bi[512 + jcol];
  const float bi_n = bi[1024 + jcol];
  const float bhn_c = bhn[jcol];
  // gate-row partition: gk0 -> i {0,3}; gk1 -> {1}; gk2 -> {2}
  const int iA = (gk == 0) ? 0 : gk;
  float holdA = h0[(size_t)(row0 + quad * 4 + iA) * H_ + jcol];
  float holdB = (gk == 0) ? h0[(size_t)(row0 + quad * 4 + 3) * H_ + jcol] : 0.f;

  // preamble: h0 -> hT (bf16, swizzled)
  for (int i = tid; i < 16 * 512; i += 384) {
    int r = i >> 9, c = i & 511;
    int c2 = (((c >> 3) ^ (r & 7)) << 3) | (c & 7);
    hT[r * 512 + c2] = f2b(h0[(size_t)(row0 + r) * H_ + c]);
  }
  // accx for t=0
  float4v accx = {0.f, 0.f, 0.f, 0.f};
  {
    const unsigned short* xp = xb + ((size_t)0 * B_ + row0 + m) * D_ + quad * 8;
#pragma unroll
    for (int k = 0; k < 8; ++k)
      accx = __builtin_amdgcn_mfma_f32_16x16x32_bf16(*(const short8*)(xp + k * 32), Bx[k], accx, 0, 0, 0);
  }

  // ---- one-time XCD-homogeneity consensus (per group; identical verdicts) --
  {
    unsigned xcc;
    asm("s_getreg_b32 %0, hwreg(HW_REG_XCC_ID)" : "=s"(xcc));
    if (tid == 0) {
      unsigned tok = xcc + 1u;
      unsigned* slot = xccbuf + wg;
      asm volatile("global_store_dword %0, %1, off sc0 sc1"
                   :: "v"(slot), "v"(tok) : "memory");
    }
    if (wave == 0) {
      unsigned val = 0xffffffffu;
      if (lane < 16) {
        const unsigned* p = xccbuf + group + 8 * lane;   // the 16 group members
        do {
          asm volatile("global_load_dword %0, %1, off sc0 sc1\n\t"
                       "s_waitcnt vmcnt(0)" : "=&v"(val) : "v"(p));
        } while (val == 0u);
      }
      unsigned ref = __shfl(val, 0, 64);
      bool ok = (lane < 16) ? (val == ref) : true;
      if (lane == 0) fast_lds = (__ballot(ok) == ~0ull) ? 1 : 0;
    }
  }
  asm volatile("s_waitcnt vmcnt(0) lgkmcnt(0)" ::: "memory");
  __syncthreads();
  const bool fast = (fast_lds != 0);

  for (int t = 0; t < T_; ++t) {
    // A: issue xa loads for t+1 first (deepest in flight: HBM latency hides
    // under the whole A+B phase), then h-MFMAs from the LDS tile.
    short8 xa[8];
    if (t < T_ - 1) {
      const unsigned short* xp = xb + ((size_t)(t + 1) * B_ + row0 + m) * D_ + quad * 8;
#pragma unroll
      for (int k = 0; k < 8; ++k)
        asm volatile("global_load_dwordx4 %0, %1, off"
                     : "=v"(xa[k]) : "v"(xp + k * 32));
    }
    float4v acch0 = {0.f, 0.f, 0.f, 0.f}, acch1 = {0.f, 0.f, 0.f, 0.f};
#pragma unroll
    for (int k = 0; k < 16; k += 2) {
      const int blk0 = (k * 4 + quad) ^ (m & 7);
      short8 a0 = *(const short8*)&hT[m * 512 + blk0 * 8];
      acch0 = __builtin_amdgcn_mfma_f32_16x16x32_bf16(a0, Bh[k], acch0, 0, 0, 0);
      const int blk1 = ((k + 1) * 4 + quad) ^ (m & 7);
      short8 a1 = *(const short8*)&hT[m * 512 + blk1 * 8];
      acch1 = __builtin_amdgcn_mfma_f32_16x16x32_bf16(a1, Bh[k + 1], acch1, 0, 0, 0);
    }
    // exchange pre-activations (h-part + x-part packed as one b64 each)
#pragma unroll
    for (int i = 0; i < 4; ++i) {
      const int idx = (quad * 4 + i) * 16 + m;
      HX v; v.h = acch0[i] + acch1[i]; v.x = accx[i];
      lds_hx[wave][idx] = v;
    }
    __syncthreads();                          // B1
    // B: gates, split across ALL 6 waves by row-index; h stored directly
    // from registers as scattered 2B stores (per-short sentinel handles
    // partial visibility).
    {
      const int wb = s * 3;
      auto do_gate = [&](int i, float& hold_ref) {
        const int idx = (quad * 4 + i) * 16 + m;
        const HX vr = lds_hx[wb + 0][idx];
        const HX vz = lds_hx[wb + 1][idx];
        const HX vn = lds_hx[wb + 2][idx];
        const float pr = vr.h + vr.x + bi_r;
        const float pz = vz.h + vz.x + bi_z;
        const float rg = 1.f / (1.f + __expf(-pr));
        const float zg = 1.f / (1.f + __expf(-pz));
        const float an = vn.x + bi_n + rg * (vn.h + bhn_c);
        const float e2 = __expf(2.f * an);          // branch-free tanh
        const float ng = 1.f - 2.f / (e2 + 1.f);
        const float hn = (1.f - zg) * ng + zg * hold_ref;
        hold_ref = hn;
        const unsigned hb = (unsigned)f2b(hn);
        unsigned short* dst = hs + ((size_t)t * B_ + row0 + quad * 4 + i) * H_ + jcol;
        if (fast)
          asm volatile("global_store_short %0, %1, off sc0"
                       :: "v"(dst), "v"(hb) : "memory");
        else
          asm volatile("global_store_short %0, %1, off sc0 sc1"
                       :: "v"(dst), "v"(hb) : "memory");
      };
      do_gate(iA, holdA);
      if (gk == 0) do_gate(3, holdB);
    }
    if (t == T_ - 1) break;                   // last h stored; done

    // wait xa only: per-wave queue = [8 xa][1-2 stores] -> counted vmcnt
    if (gk == 0)
      asm volatile("s_waitcnt vmcnt(2)"
                   : "+v"(xa[0]), "+v"(xa[1]), "+v"(xa[2]), "+v"(xa[3]),
                     "+v"(xa[4]), "+v"(xa[5]), "+v"(xa[6]), "+v"(xa[7])
                   :: "memory");
    else
      asm volatile("s_waitcnt vmcnt(1)"
                   : "+v"(xa[0]), "+v"(xa[1]), "+v"(xa[2]), "+v"(xa[3]),
                     "+v"(xa[4]), "+v"(xa[5]), "+v"(xa[6]), "+v"(xa[7])
                   :: "memory");
    __builtin_amdgcn_sched_barrier(0);
    // x-MFMAs for t+1 (covers store visibility before the poll)
    {
      float4v ax0 = {0.f, 0.f, 0.f, 0.f}, ax1 = {0.f, 0.f, 0.f, 0.f};
#pragma unroll
      for (int k = 0; k < 8; k += 2) {
        ax0 = __builtin_amdgcn_mfma_f32_16x16x32_bf16(xa[k], Bx[k], ax0, 0, 0, 0);
        ax1 = __builtin_amdgcn_mfma_f32_16x16x32_bf16(xa[k + 1], Bx[k + 1], ax1, 0, 0, 0);
      }
#pragma unroll
      for (int i = 0; i < 4; ++i) accx[i] = ax0[i] + ax1[i];
    }
    // E: poll hs[t] tile (16 rows x 512 = 1024 x 16B chunks). First pass
    // loads everything once; re-poll iterations reload ONLY invalid chunks.
    {
      const unsigned short* src = hs + ((size_t)t * B_ + row0) * H_;
      const int c0 = tid, c1 = tid + 384, c2r = tid + 768;   // waves 0-3: 3 chunks
      const short8* p0 = (const short8*)(src + (size_t)c0 * 8);
      const short8* p1 = (const short8*)(src + (size_t)c1 * 8);
      const short8* p2 = (const short8*)(src + (size_t)c2r * 8);
      short8 v0 = {}, v1 = {}, v2 = {};
      unsigned bad0, bad1, bad2;
      if (fast) { POLL("sc0") } else { POLL("sc0 sc1") }
      // gather -> hT (swizzled)
      { const int r = c0 >> 6, b2 = (c0 & 63) ^ (r & 7); *(short8*)&hT[r * 512 + b2 * 8] = v0; }
      { const int r = c1 >> 6, b2 = (c1 & 63) ^ (r & 7); *(short8*)&hT[r * 512 + b2 * 8] = v1; }
      if (wave < 4) { const int r = c2r >> 6, b2 = (c2r & 63) ^ (r & 7); *(short8*)&hT[r * 512 + b2 * 8] = v2; }
    }
    __syncthreads();                          // B3: hT ready for next step
  }
}

// ---------------------------------------------------------------- ogemm -----
__global__ __launch_bounds__(256) void ogemm_kernel(
    const unsigned short* __restrict__ hs, const unsigned short* __restrict__ WoT,
    const float* __restrict__ bo, float* __restrict__ out)
{
  const int wv = threadIdx.x >> 6, lane = threadIdx.x & 63;
  const int m = lane & 15, quad = lane >> 4;
  const int rowbase = blockIdx.x * 64 + wv * 16;
  const unsigned short* ap = hs + (size_t)(rowbase + m) * H_ + quad * 8;
  float4v acc[16];
#pragma unroll
  for (int n = 0; n < 16; ++n) { float4v z = {0.f,0.f,0.f,0.f}; acc[n] = z; }
#pragma unroll
  for (int k = 0; k < 16; ++k) {
    short8 a = *(const short8*)(ap + k * 32);
#pragma unroll
    for (int n = 0; n < 16; ++n) {
      short8 b = *(const short8*)(WoT + (size_t)(n * 16 + m) * H_ + k * 32 + quad * 8);
      acc[n] = __builtin_amdgcn_mfma_f32_16x16x32_bf16(a, b, acc[n], 0, 0, 0);
    }
  }
#pragma unroll
  for (int n = 0; n < 16; ++n) {
    const int col = n * 16 + m;
    const float bias = bo[col];
#pragma unroll
    for (int i = 0; i < 4; ++i) {
      const int r = rowbase + quad * 4 + i;
      out[(size_t)r * O_ + col] = acc[n][i] + bias;
    }
  }
}

// ---------------------------------------------------------------- launch ----
extern "C" void kernel_launch(void* const* d_in, const int* in_sizes, int n_in,
                              void* d_out, int out_size, void* d_ws, size_t ws_size,
                              hipStream_t stream)
{
  const float* x   = (const float*)d_in[0];
  const float* Wi  = (const float*)d_in[1];
  const float* bi  = (const float*)d_in[2];
  const float* Wh  = (const float*)d_in[3];
  const float* bhn = (const float*)d_in[4];
  const float* Wo  = (const float*)d_in[5];
  const float* bo  = (const float*)d_in[6];
  const float* h0  = (const float*)d_in[7];
  float* out = (float*)d_out;

  char* ws = (char*)d_ws;
  unsigned short* xb  = (unsigned short*)ws;  ws += (size_t)T_ * B_ * D_ * 2;  // 33.5 MB
  unsigned short* WhT = (unsigned short*)ws;  ws += (size_t)G_ * H_ * 2;       // 1.5 MB
  unsigned short* WiT = (unsigned short*)ws;  ws += (size_t)G_ * D_ * 2;       // 0.75 MB
  unsigned short* WoT = (unsigned short*)ws;  ws += (size_t)O_ * H_ * 2;       // 0.25 MB
  unsigned short* hs  = (unsigned short*)ws;  ws += (size_t)T_ * B_ * H_ * 2;  // 67 MB
  unsigned* xccbuf    = (unsigned*)ws;                                          // 1 KB

  prep_kernel<<<4096, 256, 0, stream>>>(x, Wi, Wh, Wo, xb, WhT, WiT, WoT, hs, xccbuf);
  scan_kernel<<<128, 384, 0, stream>>>(xb, WhT, WiT, hs, bi, bhn, h0, xccbuf);
  ogemm_kernel<<<1024, 256, 0, stream>>>(hs, WoT, bo, out);
}